// Round 9
// baseline (299.800 us; speedup 1.0000x reference)
//
#include <hip/hip_runtime.h>
#include <hip/hip_bf16.h>

// OddOneOutNet forward: B=1024, N=5, H=W=64, D=24, NK=6, META=16.
// R23: (1) cnn launch_bounds reverted to (256,4) -- R8 proved (256,5) spills
//   23MB and the occupancy gain exactly cancels the spill cost (net 0).
//   (2) head: long serial FP accumulation chains split into 2-4 independent
//   accumulators (P2/P4/P5/P6/P9/P12/P14/P15/P18/P22). Reorders fp32 sums
//   (safe vs 3.4e-3 threshold); phase structure/barriers unchanged.
// R20 head structure: ONE ROW PER BLOCK (256 thr), proven -16us at R7.
// prep_frags: proven -35us at R4.

typedef __attribute__((ext_vector_type(8))) short bf16x8;   // 8 bf16 = 4 VGPRs
typedef __attribute__((ext_vector_type(4))) float f32x4;

static __device__ __forceinline__ unsigned short f2bfu(float f) {
    return __bfloat16_as_ushort(__float2bfloat16(f));
}

// ---------------------------------------------------------------------------
// Prep kernel: one wave builds the conv2/conv3 MFMA B-fragments + biases.
//   [0 .. 768)    : b2 fragments  [3][64] x uint4   (3072 B)
//   [768 .. 2048) : b3 fragments  [5][64] x uint4   (5120 B)
//   [2048 .. 2112): bias2[lane]   [2112 .. 2176): bias3[lane]   (8704 B)
// ---------------------------------------------------------------------------
__global__ __launch_bounds__(64)
void prep_frags(const float* __restrict__ c2w, const float* __restrict__ c2b,
                const float* __restrict__ c3w, const float* __restrict__ c3b,
                float* __restrict__ fragbuf)
{
    const int lane = threadIdx.x;
    const int q = lane >> 4, oc = lane & 15;
    uint4* fb2 = (uint4*)fragbuf;          // [3][64]
    uint4* fb3 = (uint4*)fragbuf + 192;    // [5][64]

    #pragma unroll
    for (int s = 0; s < 3; ++s) {
        int t = 4 * s + q;
        union { unsigned short us[8]; uint4 v; } bb;
        #pragma unroll
        for (int j = 0; j < 8; ++j)
            bb.us[j] = (t <= 8 && oc < 12) ? f2bfu(c2w[(oc * 8 + j) * 9 + t])
                                           : (unsigned short)0;
        fb2[s * 64 + lane] = bb.v;
    }
    const int hhalf = q & 1, tq = q >> 1;
    #pragma unroll
    for (int s = 0; s < 5; ++s) {
        int slot = 2 * s + tq;
        union { unsigned short us[8]; uint4 v; } bb;
        #pragma unroll
        for (int j = 0; j < 8; ++j) {
            int ci = hhalf * 8 + j;
            bb.us[j] = (slot <= 8 && ci < 12) ? f2bfu(c3w[(oc * 12 + ci) * 9 + slot])
                                              : (unsigned short)0;
        }
        fb3[s * 64 + lane] = bb.v;
    }
    fragbuf[2048 + lane] = (oc < 12) ? c2b[oc] : 0.0f;
    fragbuf[2112 + lane] = c3b[oc];
}

// LDS: phase1 inBuf fp32 66x66 = 17,424 B
//      phase2 h1 bf16 [34][34][8] = 18,496 B (aliases inBuf)
//             h2 bf16 [18][18][16] at +18,496 = 10,368 B (disjoint from inBuf)
union CnnLds {
    float inBuf[66 * 66];
    unsigned short h1h2[34 * 34 * 8 + 18 * 18 * 16];   // h1 @0, h2 @9248 (shorts)
};

template <bool PREP>
__global__ __launch_bounds__(256, 4)
void cnn_panel_kernel(const float* __restrict__ xin,   // [BN,64,64]
                      const float* __restrict__ c1w, const float* __restrict__ c1b,
                      const float* __restrict__ c2w, const float* __restrict__ c2b,
                      const float* __restrict__ c3w, const float* __restrict__ c3b,
                      float* __restrict__ pooled,      // [BN,16] (ws)
                      const float* __restrict__ fragbuf)
{
    __shared__ CnnLds U;
    float* const inBuf = U.inBuf;
    unsigned short* const h1 = U.h1h2;           // [y][x][ci], 34x34x8
    unsigned short* const h2 = U.h1h2 + 9248;    // [y][x][ci], 18x18x16

    const int tid = threadIdx.x;
    const int img = blockIdx.x;
    const int lane = tid & 63, wave = tid >> 6;

    // ---- issue panel loads FIRST (latency hidden behind zeroing) ----
    float4 pan[4];
    {
        const float4* xv = (const float4*)(xin + (size_t)img * 4096);
        #pragma unroll
        for (int p = 0; p < 4; ++p) pan[p] = xv[tid + (p << 8)];
    }

    // ---- zero inBuf halo ring (260 cells) + all of h2 (disjoint from inBuf) ----
    if (tid < 260) {
        int y, x;
        if (tid < 66)       { y = 0;         x = tid; }
        else if (tid < 132) { y = 65;        x = tid - 66; }
        else if (tid < 196) { y = tid - 131; x = 0; }      // rows 1..64
        else                { y = tid - 195; x = 65; }
        inBuf[y * 66 + x] = 0.0f;
    }
    for (int i = tid; i < (18 * 18 * 16) / 8; i += 256)
        ((uint4*)h2)[i] = make_uint4(0, 0, 0, 0);
    __syncthreads();

    // ---- store panel into padded inBuf interior ----
    #pragma unroll
    for (int p = 0; p < 4; ++p) {
        int i = tid + (p << 8);
        int base = i << 2, y = base >> 6, x = base & 63;
        float* dst = &inBuf[(y + 1) * 66 + (x + 1)];
        dst[0] = pan[p].x; dst[1] = pan[p].y; dst[2] = pan[p].z; dst[3] = pan[p].w;
    }
    __syncthreads();

    // ---- conv1(1->8,3x3,SAME)+relu+maxpool2, channel-PAIRED (v_pk_fma_f32) ----
    uint4 h1pack[4];
    #pragma unroll
    for (int p = 0; p < 4; ++p) {
        int pos = tid + (p << 8);
        int py = pos >> 5, px = pos & 31;
        float patch[4][4];
        {
            const float* pb = &inBuf[(2 * py) * 66 + (2 * px)];
            #pragma unroll
            for (int dy = 0; dy < 4; ++dy) {
                float2 a = *(const float2*)&pb[dy * 66];
                float2 b = *(const float2*)&pb[dy * 66 + 2];
                patch[dy][0] = a.x; patch[dy][1] = a.y;
                patch[dy][2] = b.x; patch[dy][3] = b.y;
            }
        }
        float c1o[8];
        #pragma unroll
        for (int cp = 0; cp < 4; ++cp) {
            float2 bb = make_float2(c1b[2 * cp], c1b[2 * cp + 1]);
            float2 m = make_float2(-1e30f, -1e30f);
            #pragma unroll
            for (int ay = 0; ay < 2; ++ay)
                #pragma unroll
                for (int ax = 0; ax < 2; ++ax) {
                    float2 acc = bb;
                    #pragma unroll
                    for (int ky = 0; ky < 3; ++ky)
                        #pragma unroll
                        for (int kx = 0; kx < 3; ++kx) {
                            float pv = patch[ay + ky][ax + kx];
                            float2 w = make_float2(c1w[(2 * cp) * 9 + ky * 3 + kx],
                                                   c1w[(2 * cp + 1) * 9 + ky * 3 + kx]);
                            acc += make_float2(pv, pv) * w;   // v_pk_fma_f32
                        }
                    m.x = fmaxf(m.x, acc.x);
                    m.y = fmaxf(m.y, acc.y);
                }
            c1o[2 * cp]     = fmaxf(m.x, 0.0f);
            c1o[2 * cp + 1] = fmaxf(m.y, 0.0f);
        }
        uint4 v;
        v.x = (unsigned)f2bfu(c1o[0]) | ((unsigned)f2bfu(c1o[1]) << 16);
        v.y = (unsigned)f2bfu(c1o[2]) | ((unsigned)f2bfu(c1o[3]) << 16);
        v.z = (unsigned)f2bfu(c1o[4]) | ((unsigned)f2bfu(c1o[5]) << 16);
        v.w = (unsigned)f2bfu(c1o[6]) | ((unsigned)f2bfu(c1o[7]) << 16);
        h1pack[p] = v;
    }
    __syncthreads();   // inBuf reads done; safe to overwrite as h1

    // ---- write h1 interior (1 ds_write_b128 per pos) + halo zeros ----
    #pragma unroll
    for (int p = 0; p < 4; ++p) {
        int pos = tid + (p << 8);
        int py = pos >> 5, px = pos & 31;
        *(uint4*)&h1[((py + 1) * 34 + (px + 1)) * 8] = h1pack[p];
    }
    if (tid < 132) {   // halo: 34x34 - 32x32 = 132 positions x 16 B
        int r = tid, y, x;
        if (r < 34)       { y = 0;      x = r; }
        else if (r < 68)  { y = 33;     x = r - 34; }
        else if (r < 100) { y = r - 67; x = 0; }
        else              { y = r - 99; x = 33; }
        *(uint4*)&h1[(y * 34 + x) * 8] = make_uint4(0, 0, 0, 0);
    }

    // ---- conv2 B-frags: prepacked load (coalesced) or in-kernel fallback ----
    const int q = lane >> 4, mA = lane & 15, oc = lane & 15;
    int ky2[3], kx2[3];
    #pragma unroll
    for (int s = 0; s < 3; ++s) {
        int t = 4 * s + q;
        int tt = (t > 8) ? 4 : t;
        ky2[s] = tt / 3; kx2[s] = tt % 3;
    }
    bf16x8 b2f[3];
    float bias2;
    if constexpr (PREP) {
        const uint4* fb2 = (const uint4*)fragbuf;
        #pragma unroll
        for (int s = 0; s < 3; ++s) b2f[s] = *(const bf16x8*)&fb2[s * 64 + lane];
        bias2 = fragbuf[2048 + lane];
    } else {
        #pragma unroll
        for (int s = 0; s < 3; ++s) {
            int t = 4 * s + q;
            union { unsigned short us[8]; bf16x8 v; } bb;
            #pragma unroll
            for (int j = 0; j < 8; ++j)
                bb.us[j] = (t <= 8 && oc < 12) ? f2bfu(c2w[(oc * 8 + j) * 9 + t])
                                               : (unsigned short)0;
            b2f[s] = bb.v;
        }
        bias2 = (oc < 12) ? c2b[oc] : 0.0f;
    }
    __syncthreads();

    // ---- conv2 via MFMA + fused maxpool -> h2 interior ----
    for (int h = 0; h < 2; ++h) {
        #pragma unroll
        for (int Yi = 0; Yi < 4; ++Yi) {
            int Y = wave * 4 + Yi;
            float m0 = -1e30f, m1 = -1e30f;
            #pragma unroll
            for (int half = 0; half < 2; ++half) {
                int y = 2 * Y + half;
                f32x4 acc = {bias2, bias2, bias2, bias2};
                #pragma unroll
                for (int s = 0; s < 3; ++s) {
                    int off = ((y + ky2[s]) * 34 + (h * 16 + mA + kx2[s])) * 8;
                    bf16x8 a = *(const bf16x8*)&h1[off];
                    acc = __builtin_amdgcn_mfma_f32_16x16x32_bf16(a, b2f[s], acc, 0, 0, 0);
                }
                m0 = fmaxf(m0, fmaxf(acc[0], acc[1]));
                m1 = fmaxf(m1, fmaxf(acc[2], acc[3]));
            }
            if (oc < 12) {
                int X0 = h * 8 + q * 2;
                h2[((Y + 1) * 18 + (X0 + 1)) * 16 + oc] = f2bfu(fmaxf(m0, 0.0f));
                h2[((Y + 1) * 18 + (X0 + 2)) * 16 + oc] = f2bfu(fmaxf(m1, 0.0f));
            }
        }
    }
    __syncthreads();

    // ---- conv3 via MFMA + relu + mean -> pooled[img][16] ----
    {
        const int hhalf = q & 1, tq = q >> 1;
        int ky3[5], kx3[5];
        #pragma unroll
        for (int s = 0; s < 5; ++s) {
            int slot = 2 * s + tq;
            int tt = (slot > 8) ? 4 : slot;
            ky3[s] = tt / 3; kx3[s] = tt % 3;
        }
        bf16x8 b3f[5];
        float bias3;
        if constexpr (PREP) {
            const uint4* fb3 = (const uint4*)fragbuf + 192;
            #pragma unroll
            for (int s = 0; s < 5; ++s) b3f[s] = *(const bf16x8*)&fb3[s * 64 + lane];
            bias3 = fragbuf[2112 + lane];
        } else {
            #pragma unroll
            for (int s = 0; s < 5; ++s) {
                int slot = 2 * s + tq;
                union { unsigned short us[8]; bf16x8 v; } bb;
                #pragma unroll
                for (int j = 0; j < 8; ++j) {
                    int ci = hhalf * 8 + j;
                    bb.us[j] = (slot <= 8 && ci < 12) ? f2bfu(c3w[(oc * 12 + ci) * 9 + slot])
                                                      : (unsigned short)0;
                }
                b3f[s] = bb.v;
            }
            bias3 = c3b[oc];
        }
        float psum = 0.0f;
        #pragma unroll
        for (int Yi = 0; Yi < 4; ++Yi) {
            int y = wave * 4 + Yi;
            f32x4 acc = {bias3, bias3, bias3, bias3};
            #pragma unroll
            for (int s = 0; s < 5; ++s) {
                int off = ((y + ky3[s]) * 18 + (mA + kx3[s])) * 16 + hhalf * 8;
                bf16x8 a = *(const bf16x8*)&h2[off];
                acc = __builtin_amdgcn_mfma_f32_16x16x32_bf16(a, b3f[s], acc, 0, 0, 0);
            }
            psum += fmaxf(acc[0], 0.0f) + fmaxf(acc[1], 0.0f)
                  + fmaxf(acc[2], 0.0f) + fmaxf(acc[3], 0.0f);
        }
        psum += __shfl_down(psum, 32);
        psum += __shfl_down(psum, 16);
        float* red = (float*)h1;
        if (lane < 16) red[lane * 4 + wave] = psum;
        __syncthreads();
        if (tid < 16) {
            float s = red[tid * 4] + red[tid * 4 + 1] + red[tid * 4 + 2] + red[tid * 4 + 3];
            pooled[(size_t)img * 16 + tid] = s * (1.0f / 256.0f);
        }
    }
}

// ---------------------------------------------------------------------------
// Kernel B (R23): head, ONE ROW PER BLOCK (256 thr, 4 waves), grid = B.
// Long serial FMA chains split into independent accumulators (ILP).
// Summation reorder only -- thread mapping and barriers unchanged from R20.
// ---------------------------------------------------------------------------
struct RowS {
    float ph[5][16], mt[5][16];
    float zc[5][20], zmh[5][12], zm[5][12];
    float p1h[5][24], h0[5][24];
    float archl[5][6], q[5][6];
    float center[5][24], coord[5][24], x0[5][24];
    float qkv[5][72];
    float attn[2][5][5];
    float amix[5][24], aout[5][24], x1[5][24];
    float ffh[5][48], ff2o[5][24], hset[5][24], mo[5][24];
    float pq[20], pdist[20];
    float relh[20][10], relo[20][10];
    float rmean[5][10], rmax[5][10];
    float sfeat[5][146];
    float s1h[5][40];
};

__global__ __launch_bounds__(256)
void head_kernel(const float* __restrict__ pooled,    // [B*5,16]
                 const float* __restrict__ meta,      // [B,5,16]
                 const float* __restrict__ enc_fc_w, const float* __restrict__ enc_fc_b,
                 const float* __restrict__ m1_w, const float* __restrict__ m1_b,
                 const float* __restrict__ m2_w, const float* __restrict__ m2_b,
                 const float* __restrict__ p1_w, const float* __restrict__ p1_b,
                 const float* __restrict__ p2_w, const float* __restrict__ p2_b,
                 const float* __restrict__ centers,
                 const float* __restrict__ arch_w, const float* __restrict__ arch_b,
                 const float* __restrict__ in_proj_w, const float* __restrict__ in_proj_b,
                 const float* __restrict__ out_proj_w, const float* __restrict__ out_proj_b,
                 const float* __restrict__ ln1_g, const float* __restrict__ ln1_b,
                 const float* __restrict__ ff1_w, const float* __restrict__ ff1_b,
                 const float* __restrict__ ff2_w, const float* __restrict__ ff2_b,
                 const float* __restrict__ ln2_g, const float* __restrict__ ln2_b,
                 const float* __restrict__ rel1_w, const float* __restrict__ rel1_b,
                 const float* __restrict__ rel2_w, const float* __restrict__ rel2_b,
                 const float* __restrict__ s1_w, const float* __restrict__ s1_b,
                 const float* __restrict__ s2_w, const float* __restrict__ s2_b,
                 float* __restrict__ out, int q_off)
{
    __shared__ RowS H;

    const int tid = threadIdx.x;
    const int row = blockIdx.x;

    // P1: load inputs
    if (tid < 80)  ((float*)H.ph)[tid] = pooled[(size_t)row * 80 + tid];
    else if (tid < 160) ((float*)H.mt)[tid - 80] = meta[(size_t)row * 80 + (tid - 80)];
    __syncthreads();

    // P2: zc (100) | zmh (60) -- 2-acc splits
    if (tid < 100) {
        int n = tid / 20, o = tid % 20;
        float a0 = enc_fc_b[o], a1 = 0.0f;
        #pragma unroll
        for (int k = 0; k < 8; ++k)  a0 += H.ph[n][k] * enc_fc_w[o * 16 + k];
        #pragma unroll
        for (int k = 8; k < 16; ++k) a1 += H.ph[n][k] * enc_fc_w[o * 16 + k];
        H.zc[n][o] = a0 + a1;
    } else if (tid < 160) {
        int idx = tid - 100;
        int n = idx / 12, o = idx % 12;
        float a0 = m1_b[o], a1 = 0.0f;
        #pragma unroll
        for (int k = 0; k < 8; ++k)  a0 += H.mt[n][k] * m1_w[o * 16 + k];
        #pragma unroll
        for (int k = 8; k < 16; ++k) a1 += H.mt[n][k] * m1_w[o * 16 + k];
        H.zmh[n][o] = fmaxf(a0 + a1, 0.0f);
    }
    __syncthreads();

    // P3: zm (60)
    if (tid < 60) {
        int n = tid / 12, o = tid % 12;
        float a = m2_b[o];
        #pragma unroll
        for (int k = 0; k < 12; ++k) a += H.zmh[n][k] * m2_w[o * 12 + k];
        H.zm[n][o] = a;
    }
    __syncthreads();

    // P4: p1h (120) -- 4-acc split (zc 10+10, zm 6+6)
    if (tid < 120) {
        int n = tid / 24, o = tid % 24;
        float a0 = p1_b[o], a1 = 0.0f, a2 = 0.0f, a3 = 0.0f;
        #pragma unroll
        for (int k = 0; k < 10; ++k)  a0 += H.zc[n][k] * p1_w[o * 32 + k];
        #pragma unroll
        for (int k = 10; k < 20; ++k) a1 += H.zc[n][k] * p1_w[o * 32 + k];
        #pragma unroll
        for (int k = 0; k < 6; ++k)   a2 += H.zm[n][k] * p1_w[o * 32 + 20 + k];
        #pragma unroll
        for (int k = 6; k < 12; ++k)  a3 += H.zm[n][k] * p1_w[o * 32 + 20 + k];
        H.p1h[n][o] = fmaxf((a0 + a1) + (a2 + a3), 0.0f);
    }
    __syncthreads();

    // P5: h0 (120) -- 2-acc
    if (tid < 120) {
        int n = tid / 24, o = tid % 24;
        float a0 = p2_b[o], a1 = 0.0f;
        #pragma unroll
        for (int k = 0; k < 12; ++k)  a0 += H.p1h[n][k] * p2_w[o * 24 + k];
        #pragma unroll
        for (int k = 12; k < 24; ++k) a1 += H.p1h[n][k] * p2_w[o * 24 + k];
        H.h0[n][o] = a0 + a1;
    }
    __syncthreads();

    // P6: archl (30) -- 2-acc
    if (tid < 30) {
        int n = tid / 6, o = tid % 6;
        float a0 = arch_b[o], a1 = 0.0f;
        #pragma unroll
        for (int k = 0; k < 12; ++k)  a0 += H.h0[n][k] * arch_w[o * 24 + k];
        #pragma unroll
        for (int k = 12; k < 24; ++k) a1 += H.h0[n][k] * arch_w[o * 24 + k];
        H.archl[n][o] = a0 + a1;
    }
    __syncthreads();

    // P7: q softmax (5)
    if (tid < 5) {
        int n = tid;
        float m = H.archl[n][0];
        #pragma unroll
        for (int k = 1; k < 6; ++k) m = fmaxf(m, H.archl[n][k]);
        float e[6], s = 0.0f;
        #pragma unroll
        for (int k = 0; k < 6; ++k) { e[k] = __expf(H.archl[n][k] - m); s += e[k]; }
        float inv = 1.0f / s;
        #pragma unroll
        for (int k = 0; k < 6; ++k) H.q[n][k] = e[k] * inv;
    }
    __syncthreads();

    // P8: center/coord/x0 (120)
    if (tid < 120) {
        int n = tid / 24, d = tid % 24;
        float a = 0.0f;
        #pragma unroll
        for (int k = 0; k < 6; ++k) a += H.q[n][k] * centers[k * 24 + d];
        H.center[n][d] = a;
        H.coord[n][d] = H.h0[n][d] - a;
        H.x0[n][d] = H.h0[n][d] + a;
    }
    __syncthreads();

    // P9: qkv (360, 2 rounds) -- 2-acc
    for (int idx = tid; idx < 360; idx += 256) {
        int n = idx / 72, o = idx % 72;
        float a0 = in_proj_b[o], a1 = 0.0f;
        #pragma unroll
        for (int k = 0; k < 12; ++k)  a0 += H.x0[n][k] * in_proj_w[o * 24 + k];
        #pragma unroll
        for (int k = 12; k < 24; ++k) a1 += H.x0[n][k] * in_proj_w[o * 24 + k];
        H.qkv[n][o] = a0 + a1;
    }
    __syncthreads();

    // P10: attn softmax (10) | pq/pdist (20, needs q P7 + coord P8)
    if (tid < 10) {
        int h = tid / 5, i = tid % 5;
        const float scale = 0.28867513459481287f;  // 1/sqrt(12)
        float sc[5], m = -1e30f;
        for (int j = 0; j < 5; ++j) {
            float a0 = 0.0f, a1 = 0.0f;
            #pragma unroll
            for (int d = 0; d < 6; ++d)  a0 += H.qkv[i][h * 12 + d] * H.qkv[j][24 + h * 12 + d];
            #pragma unroll
            for (int d = 6; d < 12; ++d) a1 += H.qkv[i][h * 12 + d] * H.qkv[j][24 + h * 12 + d];
            sc[j] = (a0 + a1) * scale;
            m = fmaxf(m, sc[j]);
        }
        float s = 0.0f;
        #pragma unroll
        for (int j = 0; j < 5; ++j) { sc[j] = __expf(sc[j] - m); s += sc[j]; }
        float inv = 1.0f / s;
        #pragma unroll
        for (int j = 0; j < 5; ++j) H.attn[h][i][j] = sc[j] * inv;
    } else if (tid >= 32 && tid < 52) {
        int p = tid - 32;
        int i = p / 4, jj = p % 4;
        int j = jj + (jj >= i ? 1 : 0);
        float qo = 0.0f;
        #pragma unroll
        for (int k = 0; k < 6; ++k) qo += H.q[i][k] * H.q[j][k];
        H.pq[p] = qo;
        float d20 = 0.0f, d21 = 0.0f;
        #pragma unroll
        for (int k = 0; k < 12; ++k)  { float d = H.coord[i][k] - H.coord[j][k]; d20 += d * d; }
        #pragma unroll
        for (int k = 12; k < 24; ++k) { float d = H.coord[i][k] - H.coord[j][k]; d21 += d * d; }
        float d2 = d20 + d21;
        H.pdist[p] = (d2 > 0.0f) ? sqrtf(d2) : 0.0f;
    }
    __syncthreads();

    // P11: amix (120)
    if (tid < 120) {
        int i = tid / 24, o = tid % 24;
        int h = o / 12, d = o % 12;
        float a = 0.0f;
        #pragma unroll
        for (int j = 0; j < 5; ++j) a += H.attn[h][i][j] * H.qkv[j][48 + h * 12 + d];
        H.amix[i][o] = a;
    }
    __syncthreads();

    // P12: aout (120) -- 2-acc
    if (tid < 120) {
        int n = tid / 24, o = tid % 24;
        float a0 = out_proj_b[o], a1 = 0.0f;
        #pragma unroll
        for (int k = 0; k < 12; ++k)  a0 += H.amix[n][k] * out_proj_w[o * 24 + k];
        #pragma unroll
        for (int k = 12; k < 24; ++k) a1 += H.amix[n][k] * out_proj_w[o * 24 + k];
        H.aout[n][o] = H.x0[n][o] + (a0 + a1);
    }
    __syncthreads();

    // P13: ln1 (5)
    if (tid < 5) {
        int n = tid;
        float m0 = 0.0f, m1 = 0.0f;
        #pragma unroll
        for (int k = 0; k < 12; ++k)  m0 += H.aout[n][k];
        #pragma unroll
        for (int k = 12; k < 24; ++k) m1 += H.aout[n][k];
        float m = (m0 + m1) * (1.0f / 24.0f);
        float v0 = 0.0f, v1 = 0.0f;
        #pragma unroll
        for (int k = 0; k < 12; ++k)  { float d = H.aout[n][k] - m; v0 += d * d; }
        #pragma unroll
        for (int k = 12; k < 24; ++k) { float d = H.aout[n][k] - m; v1 += d * d; }
        float v = (v0 + v1) * (1.0f / 24.0f);
        float inv = 1.0f / sqrtf(v + 1e-5f);
        #pragma unroll
        for (int k = 0; k < 24; ++k)
            H.x1[n][k] = (H.aout[n][k] - m) * inv * ln1_g[k] + ln1_b[k];
    }
    __syncthreads();

    // P14: ffh (240) -- 2-acc
    if (tid < 240) {
        int n = tid / 48, o = tid % 48;
        float a0 = ff1_b[o], a1 = 0.0f;
        #pragma unroll
        for (int k = 0; k < 12; ++k)  a0 += H.x1[n][k] * ff1_w[o * 24 + k];
        #pragma unroll
        for (int k = 12; k < 24; ++k) a1 += H.x1[n][k] * ff1_w[o * 24 + k];
        H.ffh[n][o] = fmaxf(a0 + a1, 0.0f);
    }
    __syncthreads();

    // P15: ff2o (120) -- 4-acc
    if (tid < 120) {
        int n = tid / 24, o = tid % 24;
        float a0 = ff2_b[o], a1 = 0.0f, a2 = 0.0f, a3 = 0.0f;
        #pragma unroll
        for (int k = 0; k < 12; ++k)  a0 += H.ffh[n][k] * ff2_w[o * 48 + k];
        #pragma unroll
        for (int k = 12; k < 24; ++k) a1 += H.ffh[n][k] * ff2_w[o * 48 + k];
        #pragma unroll
        for (int k = 24; k < 36; ++k) a2 += H.ffh[n][k] * ff2_w[o * 48 + k];
        #pragma unroll
        for (int k = 36; k < 48; ++k) a3 += H.ffh[n][k] * ff2_w[o * 48 + k];
        H.ff2o[n][o] = H.x1[n][o] + ((a0 + a1) + (a2 + a3));
    }
    __syncthreads();

    // P16: ln2 (5)
    if (tid < 5) {
        int n = tid;
        float m0 = 0.0f, m1 = 0.0f;
        #pragma unroll
        for (int k = 0; k < 12; ++k)  m0 += H.ff2o[n][k];
        #pragma unroll
        for (int k = 12; k < 24; ++k) m1 += H.ff2o[n][k];
        float m = (m0 + m1) * (1.0f / 24.0f);
        float v0 = 0.0f, v1 = 0.0f;
        #pragma unroll
        for (int k = 0; k < 12; ++k)  { float d = H.ff2o[n][k] - m; v0 += d * d; }
        #pragma unroll
        for (int k = 12; k < 24; ++k) { float d = H.ff2o[n][k] - m; v1 += d * d; }
        float v = (v0 + v1) * (1.0f / 24.0f);
        float inv = 1.0f / sqrtf(v + 1e-5f);
        #pragma unroll
        for (int k = 0; k < 24; ++k)
            H.hset[n][k] = (H.ff2o[n][k] - m) * inv * ln2_g[k] + ln2_b[k];
    }
    __syncthreads();

    // P17: mo (120)
    if (tid < 120) {
        int n = tid / 24, d = tid % 24;
        float s = H.hset[0][d] + H.hset[1][d] + H.hset[2][d] + H.hset[3][d] + H.hset[4][d];
        H.mo[n][d] = (s - H.hset[n][d]) * 0.25f;
    }
    __syncthreads();

    // P18: relh (200) -- 6-acc (each 24-segment split 12+12)
    if (tid < 200) {
        int p = tid / 10, c = tid % 10;
        int i = p / 4, jj = p % 4;
        int j = jj + (jj >= i ? 1 : 0);
        const float* wr = rel1_w + c * 74;
        float a0 = rel1_b[c], a1 = 0.0f, a2 = 0.0f, a3 = 0.0f, a4 = 0.0f, a5 = 0.0f;
        #pragma unroll
        for (int k = 0; k < 12; ++k)  a0 += H.hset[i][k] * wr[k];
        #pragma unroll
        for (int k = 12; k < 24; ++k) a1 += H.hset[i][k] * wr[k];
        #pragma unroll
        for (int k = 0; k < 12; ++k)  a2 += H.hset[j][k] * wr[24 + k];
        #pragma unroll
        for (int k = 12; k < 24; ++k) a3 += H.hset[j][k] * wr[24 + k];
        #pragma unroll
        for (int k = 0; k < 12; ++k)  a4 += fabsf(H.coord[i][k] - H.coord[j][k]) * wr[48 + k];
        #pragma unroll
        for (int k = 12; k < 24; ++k) a5 += fabsf(H.coord[i][k] - H.coord[j][k]) * wr[48 + k];
        float a = ((a0 + a1) + (a2 + a3)) + ((a4 + a5)
                + (H.pq[p] * wr[72] + H.pdist[p] * wr[73]));
        H.relh[p][c] = fmaxf(a, 0.0f);
    }
    __syncthreads();

    // P19: relo (200)
    if (tid < 200) {
        int p = tid / 10, c = tid % 10;
        float a = rel2_b[c];
        #pragma unroll
        for (int k = 0; k < 10; ++k) a += H.relh[p][k] * rel2_w[c * 10 + k];
        H.relo[p][c] = fmaxf(a, 0.0f);
    }
    __syncthreads();

    // P20: rmean/rmax (50)
    if (tid < 50) {
        int i = tid / 10, c = tid % 10;
        float s = 0.0f, m = -1e30f;
        #pragma unroll
        for (int jj = 0; jj < 4; ++jj) {
            float v = H.relo[i * 4 + jj][c];
            s += v; m = fmaxf(m, v);
        }
        H.rmean[i][c] = s * 0.25f;
        H.rmax[i][c] = m;
    }
    __syncthreads();

    // P21: sfeat (730, 3 rounds)
    for (int idx = tid; idx < 730; idx += 256) {
        int n = idx / 146, k = idx % 146;
        float v;
        if (k < 24)       v = H.h0[n][k];
        else if (k < 48)  v = H.hset[n][k - 24];
        else if (k < 72)  v = H.center[n][k - 48];
        else if (k < 96)  v = H.coord[n][k - 72];
        else if (k < 120) v = fabsf(H.hset[n][k - 96] - H.mo[n][k - 96]);
        else if (k < 130) v = H.rmean[n][k - 120];
        else if (k < 140) v = H.rmax[n][k - 130];
        else              v = H.q[n][k - 140];
        H.sfeat[n][k] = v;
    }
    __syncthreads();

    // P22: s1h (200) -- 4-acc over the 146-chain
    if (tid < 200) {
        int n = tid / 40, o = tid % 40;
        const float* ws = s1_w + o * 146;
        float a0 = s1_b[o], a1 = 0.0f, a2 = 0.0f, a3 = 0.0f;
        #pragma unroll 4
        for (int k = 0; k < 37; ++k)    a0 += H.sfeat[n][k] * ws[k];
        #pragma unroll 4
        for (int k = 37; k < 74; ++k)   a1 += H.sfeat[n][k] * ws[k];
        #pragma unroll 4
        for (int k = 74; k < 110; ++k)  a2 += H.sfeat[n][k] * ws[k];
        #pragma unroll 4
        for (int k = 110; k < 146; ++k) a3 += H.sfeat[n][k] * ws[k];
        H.s1h[n][o] = fmaxf((a0 + a1) + (a2 + a3), 0.0f);
    }
    __syncthreads();

    // P23: logits (5) | q out (30) -- 2-acc on the 40-chain
    if (tid < 5) {
        int n = tid;
        float a0 = s2_b[0], a1 = 0.0f;
        #pragma unroll
        for (int k = 0; k < 20; ++k)  a0 += H.s1h[n][k] * s2_w[k];
        #pragma unroll
        for (int k = 20; k < 40; ++k) a1 += H.s1h[n][k] * s2_w[k];
        out[(size_t)row * 5 + n] = a0 + a1;
    }
    if (tid < 30) {
        out[q_off + (size_t)row * 30 + tid] = H.q[tid / 6][tid % 6];
    }
}

extern "C" void kernel_launch(void* const* d_in, const int* in_sizes, int n_in,
                              void* d_out, int out_size, void* d_ws, size_t ws_size,
                              hipStream_t stream) {
    const int BN = in_sizes[0] / (64 * 64);   // B*5
    const int Bb = BN / 5;                    // B

    float* pooled = (float*)d_ws;             // [BN][16] fp32
    float* fragbuf = (float*)((char*)d_ws + (size_t)BN * 64);
    const bool use_prep = ws_size >= (size_t)BN * 64 + 8704;

    if (use_prep) {
        prep_frags<<<1, 64, 0, stream>>>(
            (const float*)d_in[4], (const float*)d_in[5],
            (const float*)d_in[6], (const float*)d_in[7], fragbuf);
        cnn_panel_kernel<true><<<BN, 256, 0, stream>>>(
            (const float*)d_in[0],
            (const float*)d_in[2], (const float*)d_in[3],
            (const float*)d_in[4], (const float*)d_in[5],
            (const float*)d_in[6], (const float*)d_in[7],
            pooled, fragbuf);
    } else {
        cnn_panel_kernel<false><<<BN, 256, 0, stream>>>(
            (const float*)d_in[0],
            (const float*)d_in[2], (const float*)d_in[3],
            (const float*)d_in[4], (const float*)d_in[5],
            (const float*)d_in[6], (const float*)d_in[7],
            pooled, fragbuf);
    }

    head_kernel<<<Bb, 256, 0, stream>>>(
        pooled, (const float*)d_in[1],
        (const float*)d_in[8], (const float*)d_in[9],
        (const float*)d_in[10], (const float*)d_in[11],
        (const float*)d_in[12], (const float*)d_in[13],
        (const float*)d_in[14], (const float*)d_in[15],
        (const float*)d_in[16], (const float*)d_in[17],
        (const float*)d_in[18],
        (const float*)d_in[19], (const float*)d_in[20],
        (const float*)d_in[21], (const float*)d_in[22],
        (const float*)d_in[23], (const float*)d_in[24],
        (const float*)d_in[25], (const float*)d_in[26],
        (const float*)d_in[27], (const float*)d_in[28],
        (const float*)d_in[29], (const float*)d_in[30],
        (const float*)d_in[31], (const float*)d_in[32],
        (const float*)d_in[33], (const float*)d_in[34],
        (const float*)d_in[35], (const float*)d_in[36],
        (const float*)d_in[37], (const float*)d_in[38],
        (const float*)d_in[39], (const float*)d_in[40],
        (float*)d_out, BN);
}

// Round 10
// 277.338 us; speedup vs baseline: 1.0810x; 1.0810x over previous
//
#include <hip/hip_runtime.h>
#include <hip/hip_bf16.h>

// OddOneOutNet forward: B=1024, N=5, H=W=64, D=24, NK=6, META=16.
// R24: REVERT of R23's head ILP split (+24us regression -- head was not
//   dep-chain-bound at 4 blocks/CU; the split inflated live state across
//   22 barriers and degraded codegen). This is the R21/R22-proven best:
//   cnn (256,4)+prep (73.5us, two independent runs) + R20 head (one row
//   per 256-thr block). Measured 276.4 / 276.1 us, absmax 1.5e-5.
// Proven-out levers: prep_frags -35us (R4); head one-row-per-block -16us
//   (R7); (256,5) spills+cancels (R2,R8); fusion regresses (R5); head ILP
//   split regresses (R9).

typedef __attribute__((ext_vector_type(8))) short bf16x8;   // 8 bf16 = 4 VGPRs
typedef __attribute__((ext_vector_type(4))) float f32x4;

static __device__ __forceinline__ unsigned short f2bfu(float f) {
    return __bfloat16_as_ushort(__float2bfloat16(f));
}

// ---------------------------------------------------------------------------
// Prep kernel: one wave builds the conv2/conv3 MFMA B-fragments + biases.
//   [0 .. 768)    : b2 fragments  [3][64] x uint4   (3072 B)
//   [768 .. 2048) : b3 fragments  [5][64] x uint4   (5120 B)
//   [2048 .. 2112): bias2[lane]   [2112 .. 2176): bias3[lane]   (8704 B)
// ---------------------------------------------------------------------------
__global__ __launch_bounds__(64)
void prep_frags(const float* __restrict__ c2w, const float* __restrict__ c2b,
                const float* __restrict__ c3w, const float* __restrict__ c3b,
                float* __restrict__ fragbuf)
{
    const int lane = threadIdx.x;
    const int q = lane >> 4, oc = lane & 15;
    uint4* fb2 = (uint4*)fragbuf;          // [3][64]
    uint4* fb3 = (uint4*)fragbuf + 192;    // [5][64]

    #pragma unroll
    for (int s = 0; s < 3; ++s) {
        int t = 4 * s + q;
        union { unsigned short us[8]; uint4 v; } bb;
        #pragma unroll
        for (int j = 0; j < 8; ++j)
            bb.us[j] = (t <= 8 && oc < 12) ? f2bfu(c2w[(oc * 8 + j) * 9 + t])
                                           : (unsigned short)0;
        fb2[s * 64 + lane] = bb.v;
    }
    const int hhalf = q & 1, tq = q >> 1;
    #pragma unroll
    for (int s = 0; s < 5; ++s) {
        int slot = 2 * s + tq;
        union { unsigned short us[8]; uint4 v; } bb;
        #pragma unroll
        for (int j = 0; j < 8; ++j) {
            int ci = hhalf * 8 + j;
            bb.us[j] = (slot <= 8 && ci < 12) ? f2bfu(c3w[(oc * 12 + ci) * 9 + slot])
                                              : (unsigned short)0;
        }
        fb3[s * 64 + lane] = bb.v;
    }
    fragbuf[2048 + lane] = (oc < 12) ? c2b[oc] : 0.0f;
    fragbuf[2112 + lane] = c3b[oc];
}

// LDS: phase1 inBuf fp32 66x66 = 17,424 B
//      phase2 h1 bf16 [34][34][8] = 18,496 B (aliases inBuf)
//             h2 bf16 [18][18][16] at +18,496 = 10,368 B (disjoint from inBuf)
union CnnLds {
    float inBuf[66 * 66];
    unsigned short h1h2[34 * 34 * 8 + 18 * 18 * 16];   // h1 @0, h2 @9248 (shorts)
};

template <bool PREP>
__global__ __launch_bounds__(256, 4)
void cnn_panel_kernel(const float* __restrict__ xin,   // [BN,64,64]
                      const float* __restrict__ c1w, const float* __restrict__ c1b,
                      const float* __restrict__ c2w, const float* __restrict__ c2b,
                      const float* __restrict__ c3w, const float* __restrict__ c3b,
                      float* __restrict__ pooled,      // [BN,16] (ws)
                      const float* __restrict__ fragbuf)
{
    __shared__ CnnLds U;
    float* const inBuf = U.inBuf;
    unsigned short* const h1 = U.h1h2;           // [y][x][ci], 34x34x8
    unsigned short* const h2 = U.h1h2 + 9248;    // [y][x][ci], 18x18x16

    const int tid = threadIdx.x;
    const int img = blockIdx.x;
    const int lane = tid & 63, wave = tid >> 6;

    // ---- issue panel loads FIRST (latency hidden behind zeroing) ----
    float4 pan[4];
    {
        const float4* xv = (const float4*)(xin + (size_t)img * 4096);
        #pragma unroll
        for (int p = 0; p < 4; ++p) pan[p] = xv[tid + (p << 8)];
    }

    // ---- zero inBuf halo ring (260 cells) + all of h2 (disjoint from inBuf) ----
    if (tid < 260) {
        int y, x;
        if (tid < 66)       { y = 0;         x = tid; }
        else if (tid < 132) { y = 65;        x = tid - 66; }
        else if (tid < 196) { y = tid - 131; x = 0; }      // rows 1..64
        else                { y = tid - 195; x = 65; }
        inBuf[y * 66 + x] = 0.0f;
    }
    for (int i = tid; i < (18 * 18 * 16) / 8; i += 256)
        ((uint4*)h2)[i] = make_uint4(0, 0, 0, 0);
    __syncthreads();

    // ---- store panel into padded inBuf interior ----
    #pragma unroll
    for (int p = 0; p < 4; ++p) {
        int i = tid + (p << 8);
        int base = i << 2, y = base >> 6, x = base & 63;
        float* dst = &inBuf[(y + 1) * 66 + (x + 1)];
        dst[0] = pan[p].x; dst[1] = pan[p].y; dst[2] = pan[p].z; dst[3] = pan[p].w;
    }
    __syncthreads();

    // ---- conv1(1->8,3x3,SAME)+relu+maxpool2, channel-PAIRED (v_pk_fma_f32) ----
    uint4 h1pack[4];
    #pragma unroll
    for (int p = 0; p < 4; ++p) {
        int pos = tid + (p << 8);
        int py = pos >> 5, px = pos & 31;
        float patch[4][4];
        {
            const float* pb = &inBuf[(2 * py) * 66 + (2 * px)];
            #pragma unroll
            for (int dy = 0; dy < 4; ++dy) {
                float2 a = *(const float2*)&pb[dy * 66];
                float2 b = *(const float2*)&pb[dy * 66 + 2];
                patch[dy][0] = a.x; patch[dy][1] = a.y;
                patch[dy][2] = b.x; patch[dy][3] = b.y;
            }
        }
        float c1o[8];
        #pragma unroll
        for (int cp = 0; cp < 4; ++cp) {
            float2 bb = make_float2(c1b[2 * cp], c1b[2 * cp + 1]);
            float2 m = make_float2(-1e30f, -1e30f);
            #pragma unroll
            for (int ay = 0; ay < 2; ++ay)
                #pragma unroll
                for (int ax = 0; ax < 2; ++ax) {
                    float2 acc = bb;
                    #pragma unroll
                    for (int ky = 0; ky < 3; ++ky)
                        #pragma unroll
                        for (int kx = 0; kx < 3; ++kx) {
                            float pv = patch[ay + ky][ax + kx];
                            float2 w = make_float2(c1w[(2 * cp) * 9 + ky * 3 + kx],
                                                   c1w[(2 * cp + 1) * 9 + ky * 3 + kx]);
                            acc += make_float2(pv, pv) * w;   // v_pk_fma_f32
                        }
                    m.x = fmaxf(m.x, acc.x);
                    m.y = fmaxf(m.y, acc.y);
                }
            c1o[2 * cp]     = fmaxf(m.x, 0.0f);
            c1o[2 * cp + 1] = fmaxf(m.y, 0.0f);
        }
        uint4 v;
        v.x = (unsigned)f2bfu(c1o[0]) | ((unsigned)f2bfu(c1o[1]) << 16);
        v.y = (unsigned)f2bfu(c1o[2]) | ((unsigned)f2bfu(c1o[3]) << 16);
        v.z = (unsigned)f2bfu(c1o[4]) | ((unsigned)f2bfu(c1o[5]) << 16);
        v.w = (unsigned)f2bfu(c1o[6]) | ((unsigned)f2bfu(c1o[7]) << 16);
        h1pack[p] = v;
    }
    __syncthreads();   // inBuf reads done; safe to overwrite as h1

    // ---- write h1 interior (1 ds_write_b128 per pos) + halo zeros ----
    #pragma unroll
    for (int p = 0; p < 4; ++p) {
        int pos = tid + (p << 8);
        int py = pos >> 5, px = pos & 31;
        *(uint4*)&h1[((py + 1) * 34 + (px + 1)) * 8] = h1pack[p];
    }
    if (tid < 132) {   // halo: 34x34 - 32x32 = 132 positions x 16 B
        int r = tid, y, x;
        if (r < 34)       { y = 0;      x = r; }
        else if (r < 68)  { y = 33;     x = r - 34; }
        else if (r < 100) { y = r - 67; x = 0; }
        else              { y = r - 99; x = 33; }
        *(uint4*)&h1[(y * 34 + x) * 8] = make_uint4(0, 0, 0, 0);
    }

    // ---- conv2 B-frags: prepacked load (coalesced) or in-kernel fallback ----
    const int q = lane >> 4, mA = lane & 15, oc = lane & 15;
    int ky2[3], kx2[3];
    #pragma unroll
    for (int s = 0; s < 3; ++s) {
        int t = 4 * s + q;
        int tt = (t > 8) ? 4 : t;
        ky2[s] = tt / 3; kx2[s] = tt % 3;
    }
    bf16x8 b2f[3];
    float bias2;
    if constexpr (PREP) {
        const uint4* fb2 = (const uint4*)fragbuf;
        #pragma unroll
        for (int s = 0; s < 3; ++s) b2f[s] = *(const bf16x8*)&fb2[s * 64 + lane];
        bias2 = fragbuf[2048 + lane];
    } else {
        #pragma unroll
        for (int s = 0; s < 3; ++s) {
            int t = 4 * s + q;
            union { unsigned short us[8]; bf16x8 v; } bb;
            #pragma unroll
            for (int j = 0; j < 8; ++j)
                bb.us[j] = (t <= 8 && oc < 12) ? f2bfu(c2w[(oc * 8 + j) * 9 + t])
                                               : (unsigned short)0;
            b2f[s] = bb.v;
        }
        bias2 = (oc < 12) ? c2b[oc] : 0.0f;
    }
    __syncthreads();

    // ---- conv2 via MFMA + fused maxpool -> h2 interior ----
    for (int h = 0; h < 2; ++h) {
        #pragma unroll
        for (int Yi = 0; Yi < 4; ++Yi) {
            int Y = wave * 4 + Yi;
            float m0 = -1e30f, m1 = -1e30f;
            #pragma unroll
            for (int half = 0; half < 2; ++half) {
                int y = 2 * Y + half;
                f32x4 acc = {bias2, bias2, bias2, bias2};
                #pragma unroll
                for (int s = 0; s < 3; ++s) {
                    int off = ((y + ky2[s]) * 34 + (h * 16 + mA + kx2[s])) * 8;
                    bf16x8 a = *(const bf16x8*)&h1[off];
                    acc = __builtin_amdgcn_mfma_f32_16x16x32_bf16(a, b2f[s], acc, 0, 0, 0);
                }
                m0 = fmaxf(m0, fmaxf(acc[0], acc[1]));
                m1 = fmaxf(m1, fmaxf(acc[2], acc[3]));
            }
            if (oc < 12) {
                int X0 = h * 8 + q * 2;
                h2[((Y + 1) * 18 + (X0 + 1)) * 16 + oc] = f2bfu(fmaxf(m0, 0.0f));
                h2[((Y + 1) * 18 + (X0 + 2)) * 16 + oc] = f2bfu(fmaxf(m1, 0.0f));
            }
        }
    }
    __syncthreads();

    // ---- conv3 via MFMA + relu + mean -> pooled[img][16] ----
    {
        const int hhalf = q & 1, tq = q >> 1;
        int ky3[5], kx3[5];
        #pragma unroll
        for (int s = 0; s < 5; ++s) {
            int slot = 2 * s + tq;
            int tt = (slot > 8) ? 4 : slot;
            ky3[s] = tt / 3; kx3[s] = tt % 3;
        }
        bf16x8 b3f[5];
        float bias3;
        if constexpr (PREP) {
            const uint4* fb3 = (const uint4*)fragbuf + 192;
            #pragma unroll
            for (int s = 0; s < 5; ++s) b3f[s] = *(const bf16x8*)&fb3[s * 64 + lane];
            bias3 = fragbuf[2112 + lane];
        } else {
            #pragma unroll
            for (int s = 0; s < 5; ++s) {
                int slot = 2 * s + tq;
                union { unsigned short us[8]; bf16x8 v; } bb;
                #pragma unroll
                for (int j = 0; j < 8; ++j) {
                    int ci = hhalf * 8 + j;
                    bb.us[j] = (slot <= 8 && ci < 12) ? f2bfu(c3w[(oc * 12 + ci) * 9 + slot])
                                                      : (unsigned short)0;
                }
                b3f[s] = bb.v;
            }
            bias3 = c3b[oc];
        }
        float psum = 0.0f;
        #pragma unroll
        for (int Yi = 0; Yi < 4; ++Yi) {
            int y = wave * 4 + Yi;
            f32x4 acc = {bias3, bias3, bias3, bias3};
            #pragma unroll
            for (int s = 0; s < 5; ++s) {
                int off = ((y + ky3[s]) * 18 + (mA + kx3[s])) * 16 + hhalf * 8;
                bf16x8 a = *(const bf16x8*)&h2[off];
                acc = __builtin_amdgcn_mfma_f32_16x16x32_bf16(a, b3f[s], acc, 0, 0, 0);
            }
            psum += fmaxf(acc[0], 0.0f) + fmaxf(acc[1], 0.0f)
                  + fmaxf(acc[2], 0.0f) + fmaxf(acc[3], 0.0f);
        }
        psum += __shfl_down(psum, 32);
        psum += __shfl_down(psum, 16);
        float* red = (float*)h1;
        if (lane < 16) red[lane * 4 + wave] = psum;
        __syncthreads();
        if (tid < 16) {
            float s = red[tid * 4] + red[tid * 4 + 1] + red[tid * 4 + 2] + red[tid * 4 + 3];
            pooled[(size_t)img * 16 + tid] = s * (1.0f / 256.0f);
        }
    }
}

// ---------------------------------------------------------------------------
// Kernel B (R20): head, ONE ROW PER BLOCK (256 thr, 4 waves), grid = B.
// Phases strided over 256 threads; __syncthreads at dependence edges.
// Per-element expressions identical to the R0/R18 head (bit-identical).
// ---------------------------------------------------------------------------
struct RowS {
    float ph[5][16], mt[5][16];
    float zc[5][20], zmh[5][12], zm[5][12];
    float p1h[5][24], h0[5][24];
    float archl[5][6], q[5][6];
    float center[5][24], coord[5][24], x0[5][24];
    float qkv[5][72];
    float attn[2][5][5];
    float amix[5][24], aout[5][24], x1[5][24];
    float ffh[5][48], ff2o[5][24], hset[5][24], mo[5][24];
    float pq[20], pdist[20];
    float relh[20][10], relo[20][10];
    float rmean[5][10], rmax[5][10];
    float sfeat[5][146];
    float s1h[5][40];
};

__global__ __launch_bounds__(256)
void head_kernel(const float* __restrict__ pooled,    // [B*5,16]
                 const float* __restrict__ meta,      // [B,5,16]
                 const float* __restrict__ enc_fc_w, const float* __restrict__ enc_fc_b,
                 const float* __restrict__ m1_w, const float* __restrict__ m1_b,
                 const float* __restrict__ m2_w, const float* __restrict__ m2_b,
                 const float* __restrict__ p1_w, const float* __restrict__ p1_b,
                 const float* __restrict__ p2_w, const float* __restrict__ p2_b,
                 const float* __restrict__ centers,
                 const float* __restrict__ arch_w, const float* __restrict__ arch_b,
                 const float* __restrict__ in_proj_w, const float* __restrict__ in_proj_b,
                 const float* __restrict__ out_proj_w, const float* __restrict__ out_proj_b,
                 const float* __restrict__ ln1_g, const float* __restrict__ ln1_b,
                 const float* __restrict__ ff1_w, const float* __restrict__ ff1_b,
                 const float* __restrict__ ff2_w, const float* __restrict__ ff2_b,
                 const float* __restrict__ ln2_g, const float* __restrict__ ln2_b,
                 const float* __restrict__ rel1_w, const float* __restrict__ rel1_b,
                 const float* __restrict__ rel2_w, const float* __restrict__ rel2_b,
                 const float* __restrict__ s1_w, const float* __restrict__ s1_b,
                 const float* __restrict__ s2_w, const float* __restrict__ s2_b,
                 float* __restrict__ out, int q_off)
{
    __shared__ RowS H;

    const int tid = threadIdx.x;
    const int row = blockIdx.x;

    // P1: load inputs
    if (tid < 80)  ((float*)H.ph)[tid] = pooled[(size_t)row * 80 + tid];
    else if (tid < 160) ((float*)H.mt)[tid - 80] = meta[(size_t)row * 80 + (tid - 80)];
    __syncthreads();

    // P2: zc (100) | zmh (60)
    if (tid < 100) {
        int n = tid / 20, o = tid % 20;
        float a = enc_fc_b[o];
        #pragma unroll
        for (int k = 0; k < 16; ++k) a += H.ph[n][k] * enc_fc_w[o * 16 + k];
        H.zc[n][o] = a;
    } else if (tid < 160) {
        int idx = tid - 100;
        int n = idx / 12, o = idx % 12;
        float a = m1_b[o];
        #pragma unroll
        for (int k = 0; k < 16; ++k) a += H.mt[n][k] * m1_w[o * 16 + k];
        H.zmh[n][o] = fmaxf(a, 0.0f);
    }
    __syncthreads();

    // P3: zm (60)
    if (tid < 60) {
        int n = tid / 12, o = tid % 12;
        float a = m2_b[o];
        #pragma unroll
        for (int k = 0; k < 12; ++k) a += H.zmh[n][k] * m2_w[o * 12 + k];
        H.zm[n][o] = a;
    }
    __syncthreads();

    // P4: p1h (120)
    if (tid < 120) {
        int n = tid / 24, o = tid % 24;
        float a = p1_b[o];
        #pragma unroll
        for (int k = 0; k < 20; ++k) a += H.zc[n][k] * p1_w[o * 32 + k];
        #pragma unroll
        for (int k = 0; k < 12; ++k) a += H.zm[n][k] * p1_w[o * 32 + 20 + k];
        H.p1h[n][o] = fmaxf(a, 0.0f);
    }
    __syncthreads();

    // P5: h0 (120)
    if (tid < 120) {
        int n = tid / 24, o = tid % 24;
        float a = p2_b[o];
        #pragma unroll
        for (int k = 0; k < 24; ++k) a += H.p1h[n][k] * p2_w[o * 24 + k];
        H.h0[n][o] = a;
    }
    __syncthreads();

    // P6: archl (30)
    if (tid < 30) {
        int n = tid / 6, o = tid % 6;
        float a = arch_b[o];
        #pragma unroll
        for (int k = 0; k < 24; ++k) a += H.h0[n][k] * arch_w[o * 24 + k];
        H.archl[n][o] = a;
    }
    __syncthreads();

    // P7: q softmax (5)
    if (tid < 5) {
        int n = tid;
        float m = H.archl[n][0];
        #pragma unroll
        for (int k = 1; k < 6; ++k) m = fmaxf(m, H.archl[n][k]);
        float e[6], s = 0.0f;
        #pragma unroll
        for (int k = 0; k < 6; ++k) { e[k] = __expf(H.archl[n][k] - m); s += e[k]; }
        float inv = 1.0f / s;
        #pragma unroll
        for (int k = 0; k < 6; ++k) H.q[n][k] = e[k] * inv;
    }
    __syncthreads();

    // P8: center/coord/x0 (120)
    if (tid < 120) {
        int n = tid / 24, d = tid % 24;
        float a = 0.0f;
        #pragma unroll
        for (int k = 0; k < 6; ++k) a += H.q[n][k] * centers[k * 24 + d];
        H.center[n][d] = a;
        H.coord[n][d] = H.h0[n][d] - a;
        H.x0[n][d] = H.h0[n][d] + a;
    }
    __syncthreads();

    // P9: qkv (360, 2 rounds)
    for (int idx = tid; idx < 360; idx += 256) {
        int n = idx / 72, o = idx % 72;
        float a = in_proj_b[o];
        #pragma unroll
        for (int k = 0; k < 24; ++k) a += H.x0[n][k] * in_proj_w[o * 24 + k];
        H.qkv[n][o] = a;
    }
    __syncthreads();

    // P10: attn softmax (10) | pq/pdist (20, needs q P7 + coord P8)
    if (tid < 10) {
        int h = tid / 5, i = tid % 5;
        const float scale = 0.28867513459481287f;  // 1/sqrt(12)
        float sc[5], m = -1e30f;
        for (int j = 0; j < 5; ++j) {
            float a = 0.0f;
            #pragma unroll
            for (int d = 0; d < 12; ++d) a += H.qkv[i][h * 12 + d] * H.qkv[j][24 + h * 12 + d];
            sc[j] = a * scale;
            m = fmaxf(m, sc[j]);
        }
        float s = 0.0f;
        #pragma unroll
        for (int j = 0; j < 5; ++j) { sc[j] = __expf(sc[j] - m); s += sc[j]; }
        float inv = 1.0f / s;
        #pragma unroll
        for (int j = 0; j < 5; ++j) H.attn[h][i][j] = sc[j] * inv;
    } else if (tid >= 32 && tid < 52) {
        int p = tid - 32;
        int i = p / 4, jj = p % 4;
        int j = jj + (jj >= i ? 1 : 0);
        float qo = 0.0f;
        #pragma unroll
        for (int k = 0; k < 6; ++k) qo += H.q[i][k] * H.q[j][k];
        H.pq[p] = qo;
        float d2 = 0.0f;
        #pragma unroll
        for (int k = 0; k < 24; ++k) { float d = H.coord[i][k] - H.coord[j][k]; d2 += d * d; }
        H.pdist[p] = (d2 > 0.0f) ? sqrtf(d2) : 0.0f;
    }
    __syncthreads();

    // P11: amix (120)
    if (tid < 120) {
        int i = tid / 24, o = tid % 24;
        int h = o / 12, d = o % 12;
        float a = 0.0f;
        #pragma unroll
        for (int j = 0; j < 5; ++j) a += H.attn[h][i][j] * H.qkv[j][48 + h * 12 + d];
        H.amix[i][o] = a;
    }
    __syncthreads();

    // P12: aout (120)
    if (tid < 120) {
        int n = tid / 24, o = tid % 24;
        float a = out_proj_b[o];
        #pragma unroll
        for (int k = 0; k < 24; ++k) a += H.amix[n][k] * out_proj_w[o * 24 + k];
        H.aout[n][o] = H.x0[n][o] + a;
    }
    __syncthreads();

    // P13: ln1 (5)
    if (tid < 5) {
        int n = tid;
        float m = 0.0f;
        #pragma unroll
        for (int k = 0; k < 24; ++k) m += H.aout[n][k];
        m *= (1.0f / 24.0f);
        float v = 0.0f;
        #pragma unroll
        for (int k = 0; k < 24; ++k) { float d = H.aout[n][k] - m; v += d * d; }
        v *= (1.0f / 24.0f);
        float inv = 1.0f / sqrtf(v + 1e-5f);
        #pragma unroll
        for (int k = 0; k < 24; ++k)
            H.x1[n][k] = (H.aout[n][k] - m) * inv * ln1_g[k] + ln1_b[k];
    }
    __syncthreads();

    // P14: ffh (240)
    if (tid < 240) {
        int n = tid / 48, o = tid % 48;
        float a = ff1_b[o];
        #pragma unroll
        for (int k = 0; k < 24; ++k) a += H.x1[n][k] * ff1_w[o * 24 + k];
        H.ffh[n][o] = fmaxf(a, 0.0f);
    }
    __syncthreads();

    // P15: ff2o (120)
    if (tid < 120) {
        int n = tid / 24, o = tid % 24;
        float a = ff2_b[o];
        #pragma unroll
        for (int k = 0; k < 48; ++k) a += H.ffh[n][k] * ff2_w[o * 48 + k];
        H.ff2o[n][o] = H.x1[n][o] + a;
    }
    __syncthreads();

    // P16: ln2 (5)
    if (tid < 5) {
        int n = tid;
        float m = 0.0f;
        #pragma unroll
        for (int k = 0; k < 24; ++k) m += H.ff2o[n][k];
        m *= (1.0f / 24.0f);
        float v = 0.0f;
        #pragma unroll
        for (int k = 0; k < 24; ++k) { float d = H.ff2o[n][k] - m; v += d * d; }
        v *= (1.0f / 24.0f);
        float inv = 1.0f / sqrtf(v + 1e-5f);
        #pragma unroll
        for (int k = 0; k < 24; ++k)
            H.hset[n][k] = (H.ff2o[n][k] - m) * inv * ln2_g[k] + ln2_b[k];
    }
    __syncthreads();

    // P17: mo (120)
    if (tid < 120) {
        int n = tid / 24, d = tid % 24;
        float s = H.hset[0][d] + H.hset[1][d] + H.hset[2][d] + H.hset[3][d] + H.hset[4][d];
        H.mo[n][d] = (s - H.hset[n][d]) * 0.25f;
    }
    __syncthreads();

    // P18: relh (200)
    if (tid < 200) {
        int p = tid / 10, c = tid % 10;
        int i = p / 4, jj = p % 4;
        int j = jj + (jj >= i ? 1 : 0);
        float a = rel1_b[c];
        const float* wr = rel1_w + c * 74;
        #pragma unroll
        for (int k = 0; k < 24; ++k) a += H.hset[i][k] * wr[k];
        #pragma unroll
        for (int k = 0; k < 24; ++k) a += H.hset[j][k] * wr[24 + k];
        #pragma unroll
        for (int k = 0; k < 24; ++k) a += fabsf(H.coord[i][k] - H.coord[j][k]) * wr[48 + k];
        a += H.pq[p] * wr[72];
        a += H.pdist[p] * wr[73];
        H.relh[p][c] = fmaxf(a, 0.0f);
    }
    __syncthreads();

    // P19: relo (200)
    if (tid < 200) {
        int p = tid / 10, c = tid % 10;
        float a = rel2_b[c];
        #pragma unroll
        for (int k = 0; k < 10; ++k) a += H.relh[p][k] * rel2_w[c * 10 + k];
        H.relo[p][c] = fmaxf(a, 0.0f);
    }
    __syncthreads();

    // P20: rmean/rmax (50)
    if (tid < 50) {
        int i = tid / 10, c = tid % 10;
        float s = 0.0f, m = -1e30f;
        #pragma unroll
        for (int jj = 0; jj < 4; ++jj) {
            float v = H.relo[i * 4 + jj][c];
            s += v; m = fmaxf(m, v);
        }
        H.rmean[i][c] = s * 0.25f;
        H.rmax[i][c] = m;
    }
    __syncthreads();

    // P21: sfeat (730, 3 rounds)
    for (int idx = tid; idx < 730; idx += 256) {
        int n = idx / 146, k = idx % 146;
        float v;
        if (k < 24)       v = H.h0[n][k];
        else if (k < 48)  v = H.hset[n][k - 24];
        else if (k < 72)  v = H.center[n][k - 48];
        else if (k < 96)  v = H.coord[n][k - 72];
        else if (k < 120) v = fabsf(H.hset[n][k - 96] - H.mo[n][k - 96]);
        else if (k < 130) v = H.rmean[n][k - 120];
        else if (k < 140) v = H.rmax[n][k - 130];
        else              v = H.q[n][k - 140];
        H.sfeat[n][k] = v;
    }
    __syncthreads();

    // P22: s1h (200)
    if (tid < 200) {
        int n = tid / 40, o = tid % 40;
        float a = s1_b[o];
        #pragma unroll 8
        for (int k = 0; k < 146; ++k) a += H.sfeat[n][k] * s1_w[o * 146 + k];
        H.s1h[n][o] = fmaxf(a, 0.0f);
    }
    __syncthreads();

    // P23: logits (5) | q out (30)
    if (tid < 5) {
        int n = tid;
        float a = s2_b[0];
        #pragma unroll
        for (int k = 0; k < 40; ++k) a += H.s1h[n][k] * s2_w[k];
        out[(size_t)row * 5 + n] = a;
    }
    if (tid < 30) {
        out[q_off + (size_t)row * 30 + tid] = H.q[tid / 6][tid % 6];
    }
}

extern "C" void kernel_launch(void* const* d_in, const int* in_sizes, int n_in,
                              void* d_out, int out_size, void* d_ws, size_t ws_size,
                              hipStream_t stream) {
    const int BN = in_sizes[0] / (64 * 64);   // B*5
    const int Bb = BN / 5;                    // B

    float* pooled = (float*)d_ws;             // [BN][16] fp32
    float* fragbuf = (float*)((char*)d_ws + (size_t)BN * 64);
    const bool use_prep = ws_size >= (size_t)BN * 64 + 8704;

    if (use_prep) {
        prep_frags<<<1, 64, 0, stream>>>(
            (const float*)d_in[4], (const float*)d_in[5],
            (const float*)d_in[6], (const float*)d_in[7], fragbuf);
        cnn_panel_kernel<true><<<BN, 256, 0, stream>>>(
            (const float*)d_in[0],
            (const float*)d_in[2], (const float*)d_in[3],
            (const float*)d_in[4], (const float*)d_in[5],
            (const float*)d_in[6], (const float*)d_in[7],
            pooled, fragbuf);
    } else {
        cnn_panel_kernel<false><<<BN, 256, 0, stream>>>(
            (const float*)d_in[0],
            (const float*)d_in[2], (const float*)d_in[3],
            (const float*)d_in[4], (const float*)d_in[5],
            (const float*)d_in[6], (const float*)d_in[7],
            pooled, fragbuf);
    }

    head_kernel<<<Bb, 256, 0, stream>>>(
        pooled, (const float*)d_in[1],
        (const float*)d_in[8], (const float*)d_in[9],
        (const float*)d_in[10], (const float*)d_in[11],
        (const float*)d_in[12], (const float*)d_in[13],
        (const float*)d_in[14], (const float*)d_in[15],
        (const float*)d_in[16], (const float*)d_in[17],
        (const float*)d_in[18],
        (const float*)d_in[19], (const float*)d_in[20],
        (const float*)d_in[21], (const float*)d_in[22],
        (const float*)d_in[23], (const float*)d_in[24],
        (const float*)d_in[25], (const float*)d_in[26],
        (const float*)d_in[27], (const float*)d_in[28],
        (const float*)d_in[29], (const float*)d_in[30],
        (const float*)d_in[31], (const float*)d_in[32],
        (const float*)d_in[33], (const float*)d_in[34],
        (const float*)d_in[35], (const float*)d_in[36],
        (const float*)d_in[37], (const float*)d_in[38],
        (const float*)d_in[39], (const float*)d_in[40],
        (float*)d_out, BN);
}